// Round 2
// baseline (46415.247 us; speedup 1.0000x reference)
//
#include <hip/hip_runtime.h>

// Problem constants: B=256, T=512, F=16, H=256, L=2.
//
// ws layout (float offsets). Weights repacked as [k][unit][gate0..3]:
//   wq_ih0: [16][256][4]    off 0        (16384)
//   wq_hh0: [256][256][4]   off 16384    (262144)
//   wq_ih1: [256][256][4]   off 278528   (262144)
//   wq_hh1: [256][256][4]   off 540672   (262144)
//   biasq0: [256][4]        off 802816   (1024)   = b_ih0 + b_hh0
//   biasq1: [256][4]        off 803840   (1024)
//   h0buf:  [8g][2][256u][32b] off 804864  (131072)   double-buffered h0
//   h1buf:  [8g][2][256u][32b] off 935936  (131072)
//   hlast:  [256b][256u]    off 1067008  (65536)
//   flags:  ints            off 1132544  (1024)
// total 1133568 floats = 4.53 MB (<< ws)
#define OFF_IH0 0
#define OFF_HH0 16384
#define OFF_IH1 278528
#define OFF_HH1 540672
#define OFF_B0  802816
#define OFF_B1  803840
#define OFF_H0BUF 804864
#define OFF_H1BUF 935936
#define OFF_HLAST 1067008
#define OFF_FLAGS 1132544
#define WS_FLOATS 1133568

// dynamic LDS: layer-0 role needs (16*32 + 256*32 + 32) float4 = 139776 B (max)
#define SMEM_BYTES 139776

__global__ __launch_bounds__(256) void prep_kernel(
    const float* __restrict__ w_ih0, const float* __restrict__ w_hh0,
    const float* __restrict__ b_ih0, const float* __restrict__ b_hh0,
    const float* __restrict__ w_ih1, const float* __restrict__ w_hh1,
    const float* __restrict__ b_ih1, const float* __restrict__ b_hh1,
    float* __restrict__ ws) {
  int idx = blockIdx.x * blockDim.x + threadIdx.x;  // [0, 262144)
  int c = idx & 3;
  int m = (idx >> 2) & 255;
  int k = idx >> 10;          // k in [0,256)
  int j = c * 256 + m;        // gate row in [0,1024)
  if (k < 16) ws[OFF_IH0 + idx] = w_ih0[j * 16 + k];
  ws[OFF_HH0 + idx] = w_hh0[j * 256 + k];
  ws[OFF_IH1 + idx] = w_ih1[j * 256 + k];
  ws[OFF_HH1 + idx] = w_hh1[j * 256 + k];
  if (idx < 1024) {  // idx = m*4+c here
    ws[OFF_B0 + idx] = b_ih0[j] + b_hh0[j];
    ws[OFF_B1 + idx] = b_ih1[j] + b_hh1[j];
  }
}

__device__ __forceinline__ float sigf(float x) {
  return __fdividef(1.f, 1.f + __expf(-x));
}
__device__ __forceinline__ float tanhf_fast(float x) {
  float ax = fabsf(x);
  float e = __expf(-2.f * ax);
  float t = __fdividef(1.f - e, 1.f + e);
  return copysignf(t, x);
}
__device__ __forceinline__ float4 f4fma(float4 a, float4 w, float s) {
  a.x = fmaf(w.x, s, a.x);
  a.y = fmaf(w.y, s, a.y);
  a.z = fmaf(w.z, s, a.z);
  a.w = fmaf(w.w, s, a.w);
  return a;
}

// Block-wide wait until *f >= target (device-scope). All threads call.
__device__ __forceinline__ void waitflag(int* f, int target) {
  if (threadIdx.x == 0) {
    int guard = 0;
    while (__hip_atomic_load(f, __ATOMIC_ACQUIRE, __HIP_MEMORY_SCOPE_AGENT) < target) {
      __builtin_amdgcn_s_sleep(2);
      if (++guard > 50000000) break;  // fail (wrong result) rather than hang
    }
  }
  __syncthreads();
  __threadfence();  // ensure subsequent reads see fresh data on all threads
}

// Persistent cooperative kernel. 192 blocks = 8 groups x (8 L0 + 16 L1).
// group = blockIdx&7 (XCD-local h exchange under round-robin dispatch),
// role  = blockIdx>>3: r<8 -> layer-0 slice r (32 units); else layer-1
// slice r-8 (16 units). Weight slices live in LDS for the whole kernel;
// per-step only h crosses blocks (through L2, flag-counter protocol).
__global__ __launch_bounds__(256) void lstm_persistent(
    float* __restrict__ ws, const float* __restrict__ x,
    const int* __restrict__ lengths) {
  extern __shared__ float smem[];
  __shared__ int s_tmax;
  const int tid = threadIdx.x;
  const int g = blockIdx.x & 7;
  const int r = blockIdx.x >> 3;
  const int b0 = g * 32;
  float* h0buf = ws + OFF_H0BUF + g * 16384;  // [2][256][32]
  float* h1buf = ws + OFF_H1BUF + g * 16384;
  int* flags = (int*)(ws + OFF_FLAGS);
  int* prod_h0 = flags + g * 32;        // +=1 per L0 block per step (8/step)
  int* cons_h0 = flags + 256 + g * 32;  // +=1 per L1 block per step (16/step)
  int* prod_h1 = flags + 512 + g * 32;  // +=1 per L1 block per step (16/step)

  if (tid == 0) {
    int m = 1;
    for (int i = 0; i < 32; ++i) m = max(m, lengths[b0 + i]);
    s_tmax = m;
  }

  if (r < 8) {
    // ================= layer 0: 32 units, 32 batches =================
    const int u = tid >> 3, bq = tid & 7;  // unit, batch-quad
    const int u0 = r * 32;
    float4* lwih = (float4*)smem;   // [16][32] : k-major, unit minor
    float4* lwhh = lwih + 16 * 32;  // [256][32]
    float4* lbias = lwhh + 256 * 32;
    const float4* gih = (const float4*)(ws + OFF_IH0);  // [16][256]
    const float4* ghh = (const float4*)(ws + OFF_HH0);  // [256][256]
    for (int e = tid; e < 8192; e += 256)
      lwhh[e] = ghh[(e >> 5) * 256 + u0 + (e & 31)];
    for (int e = tid; e < 512; e += 256)
      lwih[e] = gih[(e >> 5) * 256 + u0 + (e & 31)];
    if (tid < 32) lbias[tid] = ((const float4*)(ws + OFF_B0))[u0 + tid];
    __syncthreads();
    const int tmax = s_tmax;
    const float4 bias = lbias[u];
    float c0 = 0.f, c1 = 0.f, c2 = 0.f, c3 = 0.f;
    const float4* xb0 = (const float4*)x + (size_t)(b0 + bq * 4 + 0) * 2048;
    const float4* xb1 = (const float4*)x + (size_t)(b0 + bq * 4 + 1) * 2048;
    const float4* xb2 = (const float4*)x + (size_t)(b0 + bq * 4 + 2) * 2048;
    const float4* xb3 = (const float4*)x + (size_t)(b0 + bq * 4 + 3) * 2048;

    for (int t = 0; t < tmax; ++t) {
      float4 a0 = bias, a1 = bias, a2 = bias, a3 = bias;
      // x-part: independent of flags — overlaps peers' tail compute
      #pragma unroll
      for (int i4 = 0; i4 < 4; ++i4) {
        float4 xv0 = xb0[t * 4 + i4], xv1 = xb1[t * 4 + i4];
        float4 xv2 = xb2[t * 4 + i4], xv3 = xb3[t * 4 + i4];
        const float xc0[4] = {xv0.x, xv0.y, xv0.z, xv0.w};
        const float xc1[4] = {xv1.x, xv1.y, xv1.z, xv1.w};
        const float xc2[4] = {xv2.x, xv2.y, xv2.z, xv2.w};
        const float xc3[4] = {xv3.x, xv3.y, xv3.z, xv3.w};
        #pragma unroll
        for (int ii = 0; ii < 4; ++ii) {
          float4 w = lwih[(i4 * 4 + ii) * 32 + u];
          a0 = f4fma(a0, w, xc0[ii]);
          a1 = f4fma(a1, w, xc1[ii]);
          a2 = f4fma(a2, w, xc2[ii]);
          a3 = f4fma(a3, w, xc3[ii]);
        }
      }
      // h0[t-1] ready?  (t=0: trivially true; buf1 pre-zeroed = h0[-1])
      waitflag(prod_h0, 8 * t);
      const float4* hp = (const float4*)(h0buf + ((t + 1) & 1) * 8192);
      #pragma unroll 8
      for (int k = 0; k < 256; ++k) {
        float4 h4 = hp[k * 8 + bq];        // 4 batches of h0[t-1][k]
        float4 w = lwhh[k * 32 + u];       // 4 gates, broadcast x8 lanes
        a0 = f4fma(a0, w, h4.x);
        a1 = f4fma(a1, w, h4.y);
        a2 = f4fma(a2, w, h4.z);
        a3 = f4fma(a3, w, h4.w);
      }
      float4 hv;
      c0 = sigf(a0.y) * c0 + sigf(a0.x) * tanhf_fast(a0.z);
      hv.x = sigf(a0.w) * tanhf_fast(c0);
      c1 = sigf(a1.y) * c1 + sigf(a1.x) * tanhf_fast(a1.z);
      hv.y = sigf(a1.w) * tanhf_fast(c1);
      c2 = sigf(a2.y) * c2 + sigf(a2.x) * tanhf_fast(a2.z);
      hv.z = sigf(a2.w) * tanhf_fast(c2);
      c3 = sigf(a3.y) * c3 + sigf(a3.x) * tanhf_fast(a3.z);
      hv.w = sigf(a3.w) * tanhf_fast(c3);
      // before overwriting buf[t&1] (=h0[t-2]): all 16 L1 consumed h0[t-2]
      if (t >= 2) waitflag(cons_h0, 16 * (t - 1));
      *(float4*)(h0buf + (t & 1) * 8192 + (u0 + u) * 32 + bq * 4) = hv;
      __threadfence();
      __syncthreads();
      if (tid == 0)
        __hip_atomic_fetch_add(prod_h0, 1, __ATOMIC_RELEASE,
                               __HIP_MEMORY_SCOPE_AGENT);
    }
  } else {
    // ================= layer 1: 16 units, 32 batches =================
    const int s = r - 8;
    const int u = tid >> 4, bp = tid & 15;  // unit, batch-pair
    const int u0 = s * 16;
    float4* lwih = (float4*)smem;  // [256][16]
    float4* lwhh = lwih + 4096;    // [256][16]
    float4* lbias = lwhh + 4096;
    const float4* gih = (const float4*)(ws + OFF_IH1);
    const float4* ghh = (const float4*)(ws + OFF_HH1);
    for (int e = tid; e < 4096; e += 256) {
      lwih[e] = gih[(e >> 4) * 256 + u0 + (e & 15)];
      lwhh[e] = ghh[(e >> 4) * 256 + u0 + (e & 15)];
    }
    if (tid < 16) lbias[tid] = ((const float4*)(ws + OFF_B1))[u0 + tid];
    __syncthreads();
    const int tmax = s_tmax;
    const float4 bias = lbias[u];
    const int bA = b0 + bp * 2, bB = bA + 1;
    const int lenA = lengths[bA], lenB = lengths[bB];
    float cA = 0.f, cB = 0.f;

    for (int t = 0; t < tmax; ++t) {
      float4 aA = bias, aB = bias;
      // h1[t-1] ready (own cohort lockstep; also guards buf[t&1] overwrite)
      waitflag(prod_h1, 16 * t);
      const float2* h1p = (const float2*)(h1buf + ((t + 1) & 1) * 8192);
      #pragma unroll 8
      for (int k = 0; k < 256; ++k) {
        float2 h2 = h1p[k * 16 + bp];
        float4 w = lwhh[k * 16 + u];
        aA = f4fma(aA, w, h2.x);
        aB = f4fma(aB, w, h2.y);
      }
      // h0[t] ready?
      waitflag(prod_h0, 8 * (t + 1));
      const float2* h0p = (const float2*)(h0buf + (t & 1) * 8192);
      #pragma unroll 8
      for (int k = 0; k < 256; ++k) {
        float2 h2 = h0p[k * 16 + bp];
        float4 w = lwih[k * 16 + u];
        aA = f4fma(aA, w, h2.x);
        aB = f4fma(aB, w, h2.y);
      }
      float hA, hB;
      cA = sigf(aA.y) * cA + sigf(aA.x) * tanhf_fast(aA.z);
      hA = sigf(aA.w) * tanhf_fast(cA);
      cB = sigf(aB.y) * cB + sigf(aB.x) * tanhf_fast(aB.z);
      hB = sigf(aB.w) * tanhf_fast(cB);
      *(float2*)(h1buf + (t & 1) * 8192 + (u0 + u) * 32 + bp * 2) =
          make_float2(hA, hB);
      if (t == lenA - 1) ws[OFF_HLAST + (size_t)bA * 256 + u0 + u] = hA;
      if (t == lenB - 1) ws[OFF_HLAST + (size_t)bB * 256 + u0 + u] = hB;
      __threadfence();
      __syncthreads();
      if (tid == 0) {
        __hip_atomic_fetch_add(prod_h1, 1, __ATOMIC_RELEASE,
                               __HIP_MEMORY_SCOPE_AGENT);
        __hip_atomic_fetch_add(cons_h0, 1, __ATOMIC_RELEASE,
                               __HIP_MEMORY_SCOPE_AGENT);
      }
    }
  }
}

// out[b] = relu(hlast[b]) . fc_w + fc_b   (one block per batch)
__global__ __launch_bounds__(256) void fc_kernel(
    const float* __restrict__ ws, const float* __restrict__ fc_w,
    const float* __restrict__ fc_b, float* __restrict__ out) {
  __shared__ float red[256];
  const int tid = threadIdx.x;
  const int b = blockIdx.x;
  float v = fmaxf(ws[OFF_HLAST + (size_t)b * 256 + tid], 0.f) * fc_w[tid];
  red[tid] = v;
  __syncthreads();
  #pragma unroll
  for (int s = 128; s > 0; s >>= 1) {
    if (tid < s) red[tid] += red[tid + s];
    __syncthreads();
  }
  if (tid == 0) out[b] = red[0] + fc_b[0];
}

extern "C" void kernel_launch(void* const* d_in, const int* in_sizes, int n_in,
                              void* d_out, int out_size, void* d_ws, size_t ws_size,
                              hipStream_t stream) {
  const float* x     = (const float*)d_in[0];
  const int*   lens  = (const int*)d_in[1];
  const float* w_ih0 = (const float*)d_in[2];
  const float* w_hh0 = (const float*)d_in[3];
  const float* b_ih0 = (const float*)d_in[4];
  const float* b_hh0 = (const float*)d_in[5];
  const float* w_ih1 = (const float*)d_in[6];
  const float* w_hh1 = (const float*)d_in[7];
  const float* b_ih1 = (const float*)d_in[8];
  const float* b_hh1 = (const float*)d_in[9];
  const float* fc_w  = (const float*)d_in[10];
  const float* fc_b  = (const float*)d_in[11];
  float* out = (float*)d_out;
  float* ws  = (float*)d_ws;

  // pack weights
  hipLaunchKernelGGL(prep_kernel, dim3(1024), dim3(256), 0, stream,
                     w_ih0, w_hh0, b_ih0, b_hh0, w_ih1, w_hh1, b_ih1, b_hh1, ws);
  // zero h buffers (h[-1]=0), hlast, and flag counters (ws is 0xAA-poisoned)
  hipMemsetAsync((char*)d_ws + (size_t)OFF_H0BUF * 4, 0,
                 (size_t)(WS_FLOATS - OFF_H0BUF) * 4, stream);

  hipFuncSetAttribute(reinterpret_cast<const void*>(lstm_persistent),
                      hipFuncAttributeMaxDynamicSharedMemorySize, SMEM_BYTES);
  void* args[] = {(void*)&ws, (void*)&x, (void*)&lens};
  hipLaunchCooperativeKernel(reinterpret_cast<const void*>(lstm_persistent),
                             dim3(192), dim3(256), args, SMEM_BYTES, stream);

  hipLaunchKernelGGL(fc_kernel, dim3(256), dim3(256), 0, stream,
                     ws, fc_w, fc_b, out);
}